// Round 12
// baseline (88.646 us; speedup 1.0000x reference)
//
#include <hip/hip_runtime.h>

#define NPIX 4096
#define NT 1024
#define PPT 4             // pixels per thread (contiguous strip)
#define EMPTY 0xFFFFFFFFu
#define FLAGMAGIC 0x00C0FFEEu

__global__ void ph_zero_kernel(float* out) { out[0] = 0.0f; }

__device__ __forceinline__ float kval(unsigned k) {
  unsigned u = (k & 0x80000000u) ? (k & 0x7FFFFFFFu) : ~k;
  return __uint_as_float(u);
}

__global__ __launch_bounds__(NT) void ph_pass_kernel(const float* __restrict__ x,
                                                     float* __restrict__ out,
                                                     unsigned long long* __restrict__ ws64,
                                                     int use_ws) {
  // One 64 KB pool, phase-aliased:
  //  [0,32K)  : hash (hkey 16K | hval 16K) -> compacted edge list (unsorted)
  //  [32K,48K): key32 u32[4096]            -> clobbered by node records
  //  [48K,56K): label u16[4096]            -> clobbered by node records
  //  [32K,64K): node u64[4096] = creatorKey<<32 | parent   (union-find phase)
  // R12: phase-4 compaction via one atomicAdd (edge order is don't-care:
  // it only breaks exact-float-weight ties, absent in this input); vmink
  // block-min deferred to tid 0 at phase 7 (wred[0..15] stays live now that
  // the phase-4 scans are gone). R11's fire-and-forget claims + fused
  // refind retained unchanged.
  __shared__ __align__(16) unsigned long long pool[2 * NPIX];
  __shared__ __align__(16) unsigned long long claim64[NPIX]; // 32 KB claim cells
  __shared__ unsigned long long wred[32];  // phase-1 per-wave minima (live to phase 7)
  __shared__ int s_chg[13];                // watershed + union-round flags
  __shared__ int s_M;                      // edge-list allocation counter
  __shared__ double s_sum[16];             // block reduction staging
  __shared__ float s_max[16];
  __shared__ int s_cnt[16];

  unsigned long long* sbuf = pool;
  unsigned* hkey = (unsigned*)pool;
  unsigned* hval = hkey + NPIX;
  unsigned* key32 = (unsigned*)(pool + NPIX);
  unsigned short* label = (unsigned short*)(pool + NPIX + NPIX / 2);
  unsigned long long* node = pool + NPIX;

  const int blk = blockIdx.x;            // 24 blocks: b(4) x c(3) x pass(2)
  const int b = blk / 6;
  const int rem = blk % 6;
  const int c = (rem >> 1) + 1;          // classes 1..3
  const int pass = rem & 1;              // 0 = sublevel 8-conn (H0), 1 = superlevel 4-conn (H1)
  const float* img = x + (size_t)(b * 4 + c) * NPIX;
  const int tid = threadIdx.x;
  const int lane = tid & 63, wid = tid >> 6;

  const int i0 = tid << 2;               // strip base pixel
  const bool hasL = (tid & 15) != 0;     // col base > 0
  const bool hasR = (tid & 15) != 15;    // col base < 60
  const bool hasU = tid >= 16;           // row > 0
  const bool hasD = tid < 1008;          // row < 63

  // --- phase 1: monotone keys (float4 load, uint4 store); hash+claim init
  //     as b128 writes; per-wave min staged to wred (consumed at phase 7) ---
  if (tid < 13) s_chg[tid] = 0;
  if (tid == 0) s_M = 0;
  unsigned k[4];
  {
    float4 v = ((const float4*)img)[tid];
    if (pass) { v.x = -v.x; v.y = -v.y; v.z = -v.z; v.w = -v.w; }
    unsigned u;
    u = __float_as_uint(v.x); k[0] = (u & 0x80000000u) ? ~u : (u | 0x80000000u);
    u = __float_as_uint(v.y); k[1] = (u & 0x80000000u) ? ~u : (u | 0x80000000u);
    u = __float_as_uint(v.z); k[2] = (u & 0x80000000u) ? ~u : (u | 0x80000000u);
    u = __float_as_uint(v.w); k[3] = (u & 0x80000000u) ? ~u : (u | 0x80000000u);
    uint4 t; t.x = k[0]; t.y = k[1]; t.z = k[2]; t.w = k[3];
    ((uint4*)key32)[tid] = t;
    ulonglong2 e; e.x = ~0ull; e.y = ~0ull;
    ((ulonglong2*)pool)[2 * tid] = e;            // hkey/hval = EMPTY
    ((ulonglong2*)pool)[2 * tid + 1] = e;
    ulonglong2 z; z.x = 0ull; z.y = 0ull;
    ((ulonglong2*)claim64)[2 * tid] = z;         // claims: any real claim wins
    ((ulonglong2*)claim64)[2 * tid + 1] = z;
  }
  unsigned lmin = min(min(k[0], k[1]), min(k[2], k[3]));
  for (int off = 32; off > 0; off >>= 1)
    lmin = min(lmin, (unsigned)__shfl_xor((int)lmin, off));
  if (lane == 0) wred[wid] = lmin;
  __syncthreads();                       // keys visible for phase 2

  // --- phase 2: watershed via strip-register neighborhood + 4-hop jumping ---
  unsigned ku[4], kd[4];
  unsigned kl = EMPTY, kr = EMPTY, kul = EMPTY, kur = EMPTY, kdl = EMPTY, kdr = EMPTY;
  if (hasU) { uint4 t = ((const uint4*)key32)[tid - 16]; ku[0]=t.x; ku[1]=t.y; ku[2]=t.z; ku[3]=t.w; }
  else { ku[0]=ku[1]=ku[2]=ku[3]=EMPTY; }
  if (hasD) { uint4 t = ((const uint4*)key32)[tid + 16]; kd[0]=t.x; kd[1]=t.y; kd[2]=t.z; kd[3]=t.w; }
  else { kd[0]=kd[1]=kd[2]=kd[3]=EMPTY; }
  if (hasL) kl = key32[i0 - 1];
  if (hasR) kr = key32[i0 + 4];
  if (!pass) {
    if (hasU && hasL) kul = key32[i0 - 65];
    if (hasU && hasR) kur = key32[i0 - 60];
    if (hasD && hasL) kdl = key32[i0 + 63];
    if (hasD && hasR) kdr = key32[i0 + 68];
  }
  unsigned short cur[4];
  #pragma unroll
  for (int q = 0; q < 4; q++) {
    const int i = i0 + q;
    unsigned long long best = ((unsigned long long)k[q] << 32) | (unsigned)i;
    auto upd = [&](bool v, unsigned kn, int nb) {
      if (v) {
        unsigned long long pn = ((unsigned long long)kn << 32) | (unsigned)nb;
        if (pn < best) best = pn;
      }
    };
    upd(hasU, ku[q], i - 64);
    upd(hasD, kd[q], i + 64);
    upd(q > 0 ? true : hasL, q > 0 ? k[q - 1] : kl, i - 1);
    upd(q < 3 ? true : hasR, q < 3 ? k[q + 1] : kr, i + 1);
    if (!pass) {                         // 8-conn diagonals
      upd(hasU && (q > 0 ? true : hasL), q > 0 ? ku[q - 1] : kul, i - 65);
      upd(hasU && (q < 3 ? true : hasR), q < 3 ? ku[q + 1] : kur, i - 63);
      upd(hasD && (q > 0 ? true : hasL), q > 0 ? kd[q - 1] : kdl, i + 63);
      upd(hasD && (q < 3 ? true : hasR), q < 3 ? kd[q + 1] : kdr, i + 65);
    }
    cur[q] = (unsigned short)(unsigned)best;
  }
  {
    ushort4 t; t.x = cur[0]; t.y = cur[1]; t.z = cur[2]; t.w = cur[3];
    ((ushort4*)label)[tid] = t;
  }
  __syncthreads();
  for (int round = 0; round < 6; round++) {   // 4-hop jumping, head cached in regs
    bool changed = false;
    #pragma unroll
    for (int q = 0; q < 4; q++) {
      unsigned short l = cur[q];
      unsigned short l2 = label[l];
      unsigned short l3 = label[l2];
      unsigned short l4 = label[l3];
      if (l4 != l) changed = true;
      cur[q] = l4;
    }
    ushort4 t; t.x = cur[0]; t.y = cur[1]; t.z = cur[2]; t.w = cur[3];
    ((ushort4*)label)[tid] = t;
    if (changed) s_chg[round] = 1;
    __syncthreads();
    if (!s_chg[round]) break;                  // block-uniform
  }

  // --- phase 3: inter-basin edges (register keys/labels, vector label reads),
  //     deduped to min weight per basin pair in the LDS hash ---
  auto emit = [&](unsigned la, unsigned lb, unsigned ka_, unsigned kb_) {
    if (la == lb) return;
    unsigned wkey = max(ka_, kb_);             // weight = max endpoint key
    unsigned pk = la < lb ? ((la << 12) | lb) : ((lb << 12) | la);
    unsigned h = (pk * 2654435761u) >> 20;
    while (true) {
      unsigned old = atomicCAS(&hkey[h], EMPTY, pk);
      if (old == EMPTY || old == pk) { atomicMin(&hval[h], wkey); break; }
      h = (h + 1) & (NPIX - 1);
    }
  };
  {
    unsigned short lr16 = 0, ld[4] = {0, 0, 0, 0}, ldl16 = 0, ldr16 = 0;
    if (hasR) lr16 = label[i0 + 4];
    if (hasD) { ushort4 t = ((const ushort4*)label)[tid + 16]; ld[0]=t.x; ld[1]=t.y; ld[2]=t.z; ld[3]=t.w; }
    if (!pass && hasD) {
      if (hasL) ldl16 = label[i0 + 63];
      if (hasR) ldr16 = label[i0 + 68];
    }
    emit(cur[0], cur[1], k[0], k[1]);          // right (0,1)
    emit(cur[1], cur[2], k[1], k[2]);
    emit(cur[2], cur[3], k[2], k[3]);
    if (hasR) emit(cur[3], lr16, k[3], kr);
    if (hasD) {
      emit(cur[0], ld[0], k[0], kd[0]);        // down (1,0)
      emit(cur[1], ld[1], k[1], kd[1]);
      emit(cur[2], ld[2], k[2], kd[2]);
      emit(cur[3], ld[3], k[3], kd[3]);
      if (!pass) {
        emit(cur[0], ld[1], k[0], kd[1]);      // down-right (1,1)
        emit(cur[1], ld[2], k[1], kd[2]);
        emit(cur[2], ld[3], k[2], kd[3]);
        if (hasR) emit(cur[3], ldr16, k[3], kdr);
        emit(cur[1], ld[0], k[1], kd[0]);      // down-left (1,-1)
        emit(cur[2], ld[1], k[2], kd[1]);
        emit(cur[3], ld[2], k[3], kd[2]);
        if (hasL) emit(cur[0], ldl16, k[0], kdl);
      }
    }
  }
  __syncthreads();

  // --- phase 4: compact hash (b128 scan) -> edge list via ONE atomicAdd
  //     slot allocation (order-free: ids only break exact-weight ties);
  //     node records from register keys ---
  unsigned long long item[4];
  int cnt = 0;
  {
    uint4 hk = ((const uint4*)hkey)[tid];
    uint4 hv = ((const uint4*)hval)[tid];
    if (hk.x != EMPTY) item[cnt++] = (((unsigned long long)hv.x) << 32) | hk.x;
    if (hk.y != EMPTY) item[cnt++] = (((unsigned long long)hv.y) << 32) | hk.y;
    if (hk.z != EMPTY) item[cnt++] = (((unsigned long long)hv.z) << 32) | hk.z;
    if (hk.w != EMPTY) item[cnt++] = (((unsigned long long)hv.w) << 32) | hk.w;
  }
  __syncthreads();                       // all hash reads done; pool writable
  const int base0 = cnt ? atomicAdd(&s_M, cnt) : 0;
  for (int q = 0; q < cnt; q++) sbuf[base0 + q] = item[q];
  {
    ulonglong2 n0, n1;
    n0.x = (((unsigned long long)k[0]) << 32) | (unsigned)i0;       // singletons
    n0.y = (((unsigned long long)k[1]) << 32) | (unsigned)(i0 + 1);
    n1.x = (((unsigned long long)k[2]) << 32) | (unsigned)(i0 + 2);
    n1.y = (((unsigned long long)k[3]) << 32) | (unsigned)(i0 + 3);
    ((ulonglong2*)node)[2 * tid] = n0;
    ((ulonglong2*)node)[2 * tid + 1] = n1;
  }
  if (tid < 2) s_chg[tid] = 0;           // re-zero parity flags for phase 6
  __syncthreads();                       // edges + nodes + M visible
  const int M = s_M;                     // same-address broadcast read

  // --- phase 6: ALL-AT-ONCE parallel Kruskal (claim BOTH roots, test YOUNG),
  //     2 barriers/round. Claims are fire-and-forget atomicMax (no result
  //     use -> no wait); refind walks fused (both chains in flight). ---
  double sumsq = 0.0;
  float maxp = 0.0f;
  int pcnt = 0;
  unsigned ewk[PPT], exa[PPT], exb[PPT];
  unsigned long long erA[PPT], erB[PPT];
  unsigned pmask = 0;
  #pragma unroll
  for (int q = 0; q < PPT; q++) {
    const int j = tid + q * NT;
    if (j < M) {
      const unsigned long long e = sbuf[j];
      ewk[q] = (unsigned)(e >> 32);
      const unsigned pk = (unsigned)(e & 0xFFFFFFu);
      unsigned xa = pk >> 12, xb = pk & 0xFFFu;   // basin roots (singletons now)
      exa[q] = xa; exb[q] = xb;
      erA[q] = node[xa]; erB[q] = node[xb];
      pmask |= 1u << q;                  // distinct basins by construction
    }
  }
  unsigned long long seqtag = (1ull << 44);
  #pragma unroll
  for (int q = 0; q < PPT; q++) {        // prime claims for round 1
    if (pmask & (1u << q)) {
      const int j = tid + q * NT;
      const unsigned long long myval =
          seqtag | (((unsigned long long)(~ewk[q])) << 12) | (unsigned)j;
      unsigned young, elder;
      if (erA[q] < erB[q]) { elder = exa[q]; young = exb[q]; }
      else                 { elder = exb[q]; young = exa[q]; }
      atomicMax(&claim64[young], myval);           // fire-and-forget
      atomicMax(&claim64[elder], myval);
    }
  }
  int rt = 1;
  while (true) {
    __syncthreads();                     // B_pre: claims(rt) visible
    #pragma unroll
    for (int q = 0; q < PPT; q++) {      // win-test + commit
      if (pmask & (1u << q)) {
        const int j = tid + q * NT;
        const unsigned long long myval =
            seqtag | (((unsigned long long)(~ewk[q])) << 12) | (unsigned)j;
        unsigned young, elder;
        unsigned long long yrec;
        if (erA[q] < erB[q]) { elder = exa[q]; young = exb[q]; yrec = erB[q]; }
        else                 { elder = exb[q]; young = exa[q]; yrec = erA[q]; }
        if (claim64[young] == myval) {
          const unsigned ky = (unsigned)(yrec >> 32);
          if (ewk[q] > ky) {             // strictly positive persistence
            float pers = kval(ewk[q]) - kval(ky);
            sumsq += (double)pers * (double)pers;
            maxp = fmaxf(maxp, pers);
            pcnt++;
          }
          node[young] = (yrec & 0xFFFFFFFF00000000ull) | elder;
          pmask &= ~(1u << q);
        }
      }
    }
    if (pmask) s_chg[rt & 1] = 1;        // vote: still pending
    if (tid == 0) s_chg[(rt + 1) & 1] = 0;   // reset next round's flag
    __syncthreads();                     // B_mid: commits + votes visible
    if (!s_chg[rt & 1]) break;           // block-uniform exit
    rt++; seqtag += (1ull << 44);
    #pragma unroll
    for (int q = 0; q < PPT; q++) {      // fused refind + fire-and-forget re-claim
      if (pmask & (1u << q)) {
        unsigned xa = exa[q], xb = exb[q];
        unsigned long long recA = node[xa], recB = node[xb];
        while (true) {                   // both chains stepped together
          const unsigned na = (unsigned)recA, nb2 = (unsigned)recB;
          const bool sA = (na != xa), sB = (nb2 != xb);
          if (!sA && !sB) break;
          if (sA) xa = na;
          if (sB) xb = nb2;
          if (sA) recA = node[xa];       // two independent loads in flight
          if (sB) recB = node[xb];
        }
        exa[q] = xa; exb[q] = xb; erA[q] = recA; erB[q] = recB;
        if (xa == xb) {
          pmask &= ~(1u << q);           // became a cycle edge: drop
        } else {
          const int j = tid + q * NT;
          const unsigned long long myval =
              seqtag | (((unsigned long long)(~ewk[q])) << 12) | (unsigned)j;
          unsigned young, elder;
          if (recA < recB) { elder = xa; young = xb; }
          else             { elder = xb; young = xa; }
          atomicMax(&claim64[young], myval);       // fire-and-forget
          atomicMax(&claim64[elder], myval);
        }
      }
    }
  }
  // block-wide reduction of (sumsq, maxp, pcnt): wave shfl then LDS combine
  for (int off = 32; off > 0; off >>= 1) {
    sumsq += __shfl_xor(sumsq, off);
    maxp = fmaxf(maxp, __shfl_xor(maxp, off));
    pcnt += __shfl_xor(pcnt, off);
  }
  if (lane == 0) { s_sum[wid] = sumsq; s_max[wid] = maxp; s_cnt[wid] = pcnt; }
  __syncthreads();

  // --- phase 7: per-block contribution (vmink folded from wred here) ---
  float contrib = 0.0f;
  if (tid == 0) {
    #pragma unroll
    for (int w = 1; w < 16; w++) {
      sumsq += s_sum[w];
      maxp = fmaxf(maxp, s_max[w]);
      pcnt += s_cnt[w];
    }
    unsigned vmink = (unsigned)wred[0];
    #pragma unroll
    for (int w = 1; w < 16; w++) vmink = min(vmink, (unsigned)wred[w]);
    if (pass == 0) {
      const int nf0 = (c == 3) ? 2 : 1;      // TOPO H0: c1->1, c2->1, c3->2
      float vmin = kval(vmink);              // essential birth = global min
      if (nf0 == 1) {
        contrib = vmin * vmin + (float)sumsq;
      } else if (pcnt >= 1) {
        contrib = vmin * vmin + (1.0f - maxp) * (1.0f - maxp)
                + (float)(sumsq - (double)maxp * (double)maxp);
      } else {
        contrib = vmin * vmin + 1.0f;
      }
    } else {
      const int nf1 = (c == 2) ? 1 : 0;      // TOPO H1: c1->0, c2->1, c3->0
      if (nf1 == 0) contrib = (float)sumsq;
      else contrib = (pcnt >= 1)
        ? ((1.0f - maxp) * (1.0f - maxp) + (float)(sumsq - (double)maxp * (double)maxp))
        : 1.0f;
    }
    contrib *= 0.25f;                        // / B, B = 4
    if (use_ws) {
      // publish (value<<32 | magic) in one device-scope atomic — no fence needed
      atomicExch(&ws64[blk],
                 (((unsigned long long)__float_as_uint(contrib)) << 32) | FLAGMAGIC);
    } else {
      atomicAdd(out, contrib);               // out pre-zeroed by ph_zero_kernel
    }
  }
  // --- block 0 wave 0: gather all 24 contributions, write out ---
  if (use_ws && blk == 0 && wid == 0) {
    float v = 0.0f;
    if (lane < 24) {
      while (true) {
        unsigned long long r = atomicAdd(&ws64[lane], 0ull);  // device-coherent read
        if ((unsigned)r == FLAGMAGIC) { v = __uint_as_float((unsigned)(r >> 32)); break; }
      }
    }
    for (int off = 32; off > 0; off >>= 1) v += __shfl_xor(v, off);
    if (lane == 0) out[0] = v;
  }
}

extern "C" void kernel_launch(void* const* d_in, const int* in_sizes, int n_in,
                              void* d_out, int out_size, void* d_ws, size_t ws_size,
                              hipStream_t stream) {
  const float* x = (const float*)d_in[0];
  float* out = (float*)d_out;
  if (ws_size >= 24 * sizeof(unsigned long long)) {
    ph_pass_kernel<<<24, NT, 0, stream>>>(x, out, (unsigned long long*)d_ws, 1);
  } else {
    ph_zero_kernel<<<1, 1, 0, stream>>>(out);
    ph_pass_kernel<<<24, NT, 0, stream>>>(x, out, nullptr, 0);
  }
}

// Round 13
// 86.130 us; speedup vs baseline: 1.0292x; 1.0292x over previous
//
#include <hip/hip_runtime.h>

#define NPIX 4096
#define NT 1024
#define PPT 4             // pixels per thread (contiguous strip)
#define EMPTY 0xFFFFFFFFu
#define FLAGMAGIC 0x00C0FFEEu

__global__ void ph_zero_kernel(float* out) { out[0] = 0.0f; }

__device__ __forceinline__ float kval(unsigned k) {
  unsigned u = (k & 0x80000000u) ? (k & 0x7FFFFFFFu) : ~k;
  return __uint_as_float(u);
}

__global__ __launch_bounds__(NT) void ph_pass_kernel(const float* __restrict__ x,
                                                     float* __restrict__ out,
                                                     unsigned long long* __restrict__ ws64,
                                                     int use_ws) {
  // One 64 KB pool, phase-aliased:
  //  [0,32K)  : hash (hkey 16K | hval 16K) -> compacted edge list (unsorted)
  //  [32K,48K): key32 u32[4096]            -> clobbered by node records
  //  [48K,56K): label u16[4096]            -> clobbered by node records
  //  [32K,64K): node u64[4096] = creatorKey<<32 | parent   (union-find phase)
  // R13 = exact revert to R11 (best measured). R12's single-cell atomicAdd
  // compaction serialized all 1024 threads on one LDS address (~5 us) —
  // worse than the shfl scan it replaced. Keep: fire-and-forget claim
  // atomics (no read-filter) + fused refind walks (both chains in flight).
  __shared__ __align__(16) unsigned long long pool[2 * NPIX];
  __shared__ __align__(16) unsigned long long claim64[NPIX]; // 32 KB claim cells
  __shared__ unsigned long long wred[32];  // wave staging: [0..15] raw, [16..31] scanned
  __shared__ int s_chg[13];                // watershed + union-round flags
  __shared__ double s_sum[16];             // block reduction staging
  __shared__ float s_max[16];
  __shared__ int s_cnt[16];

  unsigned long long* sbuf = pool;
  unsigned* hkey = (unsigned*)pool;
  unsigned* hval = hkey + NPIX;
  unsigned* key32 = (unsigned*)(pool + NPIX);
  unsigned short* label = (unsigned short*)(pool + NPIX + NPIX / 2);
  unsigned long long* node = pool + NPIX;

  const int blk = blockIdx.x;            // 24 blocks: b(4) x c(3) x pass(2)
  const int b = blk / 6;
  const int rem = blk % 6;
  const int c = (rem >> 1) + 1;          // classes 1..3
  const int pass = rem & 1;              // 0 = sublevel 8-conn (H0), 1 = superlevel 4-conn (H1)
  const float* img = x + (size_t)(b * 4 + c) * NPIX;
  const int tid = threadIdx.x;
  const int lane = tid & 63, wid = tid >> 6;

  const int i0 = tid << 2;               // strip base pixel
  const bool hasL = (tid & 15) != 0;     // col base > 0
  const bool hasR = (tid & 15) != 15;    // col base < 60
  const bool hasU = tid >= 16;           // row > 0
  const bool hasD = tid < 1008;          // row < 63

  // --- phase 1: monotone keys (float4 load, uint4 store); hash+claim init
  //     as b128 writes; block min ---
  if (tid < 13) s_chg[tid] = 0;
  unsigned k[4];
  {
    float4 v = ((const float4*)img)[tid];
    if (pass) { v.x = -v.x; v.y = -v.y; v.z = -v.z; v.w = -v.w; }
    unsigned u;
    u = __float_as_uint(v.x); k[0] = (u & 0x80000000u) ? ~u : (u | 0x80000000u);
    u = __float_as_uint(v.y); k[1] = (u & 0x80000000u) ? ~u : (u | 0x80000000u);
    u = __float_as_uint(v.z); k[2] = (u & 0x80000000u) ? ~u : (u | 0x80000000u);
    u = __float_as_uint(v.w); k[3] = (u & 0x80000000u) ? ~u : (u | 0x80000000u);
    uint4 t; t.x = k[0]; t.y = k[1]; t.z = k[2]; t.w = k[3];
    ((uint4*)key32)[tid] = t;
    ulonglong2 e; e.x = ~0ull; e.y = ~0ull;
    ((ulonglong2*)pool)[2 * tid] = e;            // hkey/hval = EMPTY
    ((ulonglong2*)pool)[2 * tid + 1] = e;
    ulonglong2 z; z.x = 0ull; z.y = 0ull;
    ((ulonglong2*)claim64)[2 * tid] = z;         // claims: any real claim wins
    ((ulonglong2*)claim64)[2 * tid + 1] = z;
  }
  unsigned lmin = min(min(k[0], k[1]), min(k[2], k[3]));
  for (int off = 32; off > 0; off >>= 1)
    lmin = min(lmin, (unsigned)__shfl_xor((int)lmin, off));
  if (lane == 0) wred[wid] = lmin;
  __syncthreads();                       // keys visible for phase 2
  unsigned vmink = (unsigned)wred[0];
  #pragma unroll
  for (int w = 1; w < 16; w++) vmink = min(vmink, (unsigned)wred[w]);

  // --- phase 2: watershed via strip-register neighborhood + 4-hop jumping ---
  unsigned ku[4], kd[4];
  unsigned kl = EMPTY, kr = EMPTY, kul = EMPTY, kur = EMPTY, kdl = EMPTY, kdr = EMPTY;
  if (hasU) { uint4 t = ((const uint4*)key32)[tid - 16]; ku[0]=t.x; ku[1]=t.y; ku[2]=t.z; ku[3]=t.w; }
  else { ku[0]=ku[1]=ku[2]=ku[3]=EMPTY; }
  if (hasD) { uint4 t = ((const uint4*)key32)[tid + 16]; kd[0]=t.x; kd[1]=t.y; kd[2]=t.z; kd[3]=t.w; }
  else { kd[0]=kd[1]=kd[2]=kd[3]=EMPTY; }
  if (hasL) kl = key32[i0 - 1];
  if (hasR) kr = key32[i0 + 4];
  if (!pass) {
    if (hasU && hasL) kul = key32[i0 - 65];
    if (hasU && hasR) kur = key32[i0 - 60];
    if (hasD && hasL) kdl = key32[i0 + 63];
    if (hasD && hasR) kdr = key32[i0 + 68];
  }
  unsigned short cur[4];
  #pragma unroll
  for (int q = 0; q < 4; q++) {
    const int i = i0 + q;
    unsigned long long best = ((unsigned long long)k[q] << 32) | (unsigned)i;
    auto upd = [&](bool v, unsigned kn, int nb) {
      if (v) {
        unsigned long long pn = ((unsigned long long)kn << 32) | (unsigned)nb;
        if (pn < best) best = pn;
      }
    };
    upd(hasU, ku[q], i - 64);
    upd(hasD, kd[q], i + 64);
    upd(q > 0 ? true : hasL, q > 0 ? k[q - 1] : kl, i - 1);
    upd(q < 3 ? true : hasR, q < 3 ? k[q + 1] : kr, i + 1);
    if (!pass) {                         // 8-conn diagonals
      upd(hasU && (q > 0 ? true : hasL), q > 0 ? ku[q - 1] : kul, i - 65);
      upd(hasU && (q < 3 ? true : hasR), q < 3 ? ku[q + 1] : kur, i - 63);
      upd(hasD && (q > 0 ? true : hasL), q > 0 ? kd[q - 1] : kdl, i + 63);
      upd(hasD && (q < 3 ? true : hasR), q < 3 ? kd[q + 1] : kdr, i + 65);
    }
    cur[q] = (unsigned short)(unsigned)best;
  }
  {
    ushort4 t; t.x = cur[0]; t.y = cur[1]; t.z = cur[2]; t.w = cur[3];
    ((ushort4*)label)[tid] = t;
  }
  __syncthreads();
  for (int round = 0; round < 6; round++) {   // 4-hop jumping, head cached in regs
    bool changed = false;
    #pragma unroll
    for (int q = 0; q < 4; q++) {
      unsigned short l = cur[q];
      unsigned short l2 = label[l];
      unsigned short l3 = label[l2];
      unsigned short l4 = label[l3];
      if (l4 != l) changed = true;
      cur[q] = l4;
    }
    ushort4 t; t.x = cur[0]; t.y = cur[1]; t.z = cur[2]; t.w = cur[3];
    ((ushort4*)label)[tid] = t;
    if (changed) s_chg[round] = 1;
    __syncthreads();
    if (!s_chg[round]) break;                  // block-uniform
  }

  // --- phase 3: inter-basin edges (register keys/labels, vector label reads),
  //     deduped to min weight per basin pair in the LDS hash ---
  auto emit = [&](unsigned la, unsigned lb, unsigned ka_, unsigned kb_) {
    if (la == lb) return;
    unsigned wkey = max(ka_, kb_);             // weight = max endpoint key
    unsigned pk = la < lb ? ((la << 12) | lb) : ((lb << 12) | la);
    unsigned h = (pk * 2654435761u) >> 20;
    while (true) {
      unsigned old = atomicCAS(&hkey[h], EMPTY, pk);
      if (old == EMPTY || old == pk) { atomicMin(&hval[h], wkey); break; }
      h = (h + 1) & (NPIX - 1);
    }
  };
  {
    unsigned short lr16 = 0, ld[4] = {0, 0, 0, 0}, ldl16 = 0, ldr16 = 0;
    if (hasR) lr16 = label[i0 + 4];
    if (hasD) { ushort4 t = ((const ushort4*)label)[tid + 16]; ld[0]=t.x; ld[1]=t.y; ld[2]=t.z; ld[3]=t.w; }
    if (!pass && hasD) {
      if (hasL) ldl16 = label[i0 + 63];
      if (hasR) ldr16 = label[i0 + 68];
    }
    emit(cur[0], cur[1], k[0], k[1]);          // right (0,1)
    emit(cur[1], cur[2], k[1], k[2]);
    emit(cur[2], cur[3], k[2], k[3]);
    if (hasR) emit(cur[3], lr16, k[3], kr);
    if (hasD) {
      emit(cur[0], ld[0], k[0], kd[0]);        // down (1,0)
      emit(cur[1], ld[1], k[1], kd[1]);
      emit(cur[2], ld[2], k[2], kd[2]);
      emit(cur[3], ld[3], k[3], kd[3]);
      if (!pass) {
        emit(cur[0], ld[1], k[0], kd[1]);      // down-right (1,1)
        emit(cur[1], ld[2], k[1], kd[2]);
        emit(cur[2], ld[3], k[2], kd[3]);
        if (hasR) emit(cur[3], ldr16, k[3], kdr);
        emit(cur[1], ld[0], k[1], kd[0]);      // down-left (1,-1)
        emit(cur[2], ld[1], k[2], kd[1]);
        emit(cur[3], ld[2], k[3], kd[2]);
        if (hasL) emit(cur[0], ldl16, k[0], kdl);
      }
    }
  }
  __syncthreads();

  // --- phase 4: compact hash (b128 scan, same slot order) -> edge list;
  //     node records from register keys ---
  unsigned long long item[4];
  int cnt = 0;
  {
    uint4 hk = ((const uint4*)hkey)[tid];
    uint4 hv = ((const uint4*)hval)[tid];
    if (hk.x != EMPTY) item[cnt++] = (((unsigned long long)hv.x) << 32) | hk.x;
    if (hk.y != EMPTY) item[cnt++] = (((unsigned long long)hv.y) << 32) | hk.y;
    if (hk.z != EMPTY) item[cnt++] = (((unsigned long long)hv.z) << 32) | hk.z;
    if (hk.w != EMPTY) item[cnt++] = (((unsigned long long)hv.w) << 32) | hk.w;
  }
  __syncthreads();                       // all reads of pool[0..56K) done
  unsigned inc = (unsigned)cnt;
  for (int off = 1; off < 64; off <<= 1) {   // intra-wave inclusive scan
    unsigned v = __shfl_up(inc, off);
    if (lane >= off) inc += v;
  }
  if (lane == 63) wred[wid] = inc;
  __syncthreads();
  if (wid == 0) {                        // scan the 16 wave totals in wave 0
    unsigned wv = (lane < 16) ? (unsigned)wred[lane] : 0u;
    for (int off = 1; off < 16; off <<= 1) {
      unsigned v = __shfl_up(wv, off);
      if (lane >= off) wv += v;
    }
    if (lane < 16) wred[16 + lane] = wv;
  }
  __syncthreads();
  const int M = (int)wred[31];
  const int base0 = (int)((wid ? (unsigned)wred[16 + wid - 1] : 0u) + inc) - cnt;
  for (int q = 0; q < cnt; q++) sbuf[base0 + q] = item[q];
  {
    ulonglong2 n0, n1;
    n0.x = (((unsigned long long)k[0]) << 32) | (unsigned)i0;       // singletons
    n0.y = (((unsigned long long)k[1]) << 32) | (unsigned)(i0 + 1);
    n1.x = (((unsigned long long)k[2]) << 32) | (unsigned)(i0 + 2);
    n1.y = (((unsigned long long)k[3]) << 32) | (unsigned)(i0 + 3);
    ((ulonglong2*)node)[2 * tid] = n0;
    ((ulonglong2*)node)[2 * tid + 1] = n1;
  }
  if (tid < 2) s_chg[tid] = 0;           // re-zero parity flags for phase 6
  __syncthreads();

  // --- phase 6: ALL-AT-ONCE parallel Kruskal (claim BOTH roots, test YOUNG),
  //     2 barriers/round. Claims are fire-and-forget atomicMax (no result
  //     use -> no wait); refind walks fused (both chains in flight). ---
  double sumsq = 0.0;
  float maxp = 0.0f;
  int pcnt = 0;
  unsigned ewk[PPT], exa[PPT], exb[PPT];
  unsigned long long erA[PPT], erB[PPT];
  unsigned pmask = 0;
  #pragma unroll
  for (int q = 0; q < PPT; q++) {
    const int j = tid + q * NT;
    if (j < M) {
      const unsigned long long e = sbuf[j];
      ewk[q] = (unsigned)(e >> 32);
      const unsigned pk = (unsigned)(e & 0xFFFFFFu);
      unsigned xa = pk >> 12, xb = pk & 0xFFFu;   // basin roots (singletons now)
      exa[q] = xa; exb[q] = xb;
      erA[q] = node[xa]; erB[q] = node[xb];
      pmask |= 1u << q;                  // distinct basins by construction
    }
  }
  unsigned long long seqtag = (1ull << 44);
  #pragma unroll
  for (int q = 0; q < PPT; q++) {        // prime claims for round 1
    if (pmask & (1u << q)) {
      const int j = tid + q * NT;
      const unsigned long long myval =
          seqtag | (((unsigned long long)(~ewk[q])) << 12) | (unsigned)j;
      unsigned young, elder;
      if (erA[q] < erB[q]) { elder = exa[q]; young = exb[q]; }
      else                 { elder = exb[q]; young = exa[q]; }
      atomicMax(&claim64[young], myval);           // fire-and-forget
      atomicMax(&claim64[elder], myval);
    }
  }
  int rt = 1;
  while (true) {
    __syncthreads();                     // B_pre: claims(rt) visible
    #pragma unroll
    for (int q = 0; q < PPT; q++) {      // win-test + commit
      if (pmask & (1u << q)) {
        const int j = tid + q * NT;
        const unsigned long long myval =
            seqtag | (((unsigned long long)(~ewk[q])) << 12) | (unsigned)j;
        unsigned young, elder;
        unsigned long long yrec;
        if (erA[q] < erB[q]) { elder = exa[q]; young = exb[q]; yrec = erB[q]; }
        else                 { elder = exb[q]; young = exa[q]; yrec = erA[q]; }
        if (claim64[young] == myval) {
          const unsigned ky = (unsigned)(yrec >> 32);
          if (ewk[q] > ky) {             // strictly positive persistence
            float pers = kval(ewk[q]) - kval(ky);
            sumsq += (double)pers * (double)pers;
            maxp = fmaxf(maxp, pers);
            pcnt++;
          }
          node[young] = (yrec & 0xFFFFFFFF00000000ull) | elder;
          pmask &= ~(1u << q);
        }
      }
    }
    if (pmask) s_chg[rt & 1] = 1;        // vote: still pending
    if (tid == 0) s_chg[(rt + 1) & 1] = 0;   // reset next round's flag
    __syncthreads();                     // B_mid: commits + votes visible
    if (!s_chg[rt & 1]) break;           // block-uniform exit
    rt++; seqtag += (1ull << 44);
    #pragma unroll
    for (int q = 0; q < PPT; q++) {      // fused refind + fire-and-forget re-claim
      if (pmask & (1u << q)) {
        unsigned xa = exa[q], xb = exb[q];
        unsigned long long recA = node[xa], recB = node[xb];
        while (true) {                   // both chains stepped together
          const unsigned na = (unsigned)recA, nb2 = (unsigned)recB;
          const bool sA = (na != xa), sB = (nb2 != xb);
          if (!sA && !sB) break;
          if (sA) xa = na;
          if (sB) xb = nb2;
          if (sA) recA = node[xa];       // two independent loads in flight
          if (sB) recB = node[xb];
        }
        exa[q] = xa; exb[q] = xb; erA[q] = recA; erB[q] = recB;
        if (xa == xb) {
          pmask &= ~(1u << q);           // became a cycle edge: drop
        } else {
          const int j = tid + q * NT;
          const unsigned long long myval =
              seqtag | (((unsigned long long)(~ewk[q])) << 12) | (unsigned)j;
          unsigned young, elder;
          if (recA < recB) { elder = xa; young = xb; }
          else             { elder = xb; young = xa; }
          atomicMax(&claim64[young], myval);       // fire-and-forget
          atomicMax(&claim64[elder], myval);
        }
      }
    }
  }
  // block-wide reduction of (sumsq, maxp, pcnt): wave shfl then LDS combine
  for (int off = 32; off > 0; off >>= 1) {
    sumsq += __shfl_xor(sumsq, off);
    maxp = fmaxf(maxp, __shfl_xor(maxp, off));
    pcnt += __shfl_xor(pcnt, off);
  }
  if (lane == 0) { s_sum[wid] = sumsq; s_max[wid] = maxp; s_cnt[wid] = pcnt; }
  __syncthreads();

  // --- phase 7: per-block contribution ---
  float contrib = 0.0f;
  if (tid == 0) {
    #pragma unroll
    for (int w = 1; w < 16; w++) {
      sumsq += s_sum[w];
      maxp = fmaxf(maxp, s_max[w]);
      pcnt += s_cnt[w];
    }
    if (pass == 0) {
      const int nf0 = (c == 3) ? 2 : 1;      // TOPO H0: c1->1, c2->1, c3->2
      float vmin = kval(vmink);              // essential birth = global min
      if (nf0 == 1) {
        contrib = vmin * vmin + (float)sumsq;
      } else if (pcnt >= 1) {
        contrib = vmin * vmin + (1.0f - maxp) * (1.0f - maxp)
                + (float)(sumsq - (double)maxp * (double)maxp);
      } else {
        contrib = vmin * vmin + 1.0f;
      }
    } else {
      const int nf1 = (c == 2) ? 1 : 0;      // TOPO H1: c1->0, c2->1, c3->0
      if (nf1 == 0) contrib = (float)sumsq;
      else contrib = (pcnt >= 1)
        ? ((1.0f - maxp) * (1.0f - maxp) + (float)(sumsq - (double)maxp * (double)maxp))
        : 1.0f;
    }
    contrib *= 0.25f;                        // / B, B = 4
    if (use_ws) {
      // publish (value<<32 | magic) in one device-scope atomic — no fence needed
      atomicExch(&ws64[blk],
                 (((unsigned long long)__float_as_uint(contrib)) << 32) | FLAGMAGIC);
    } else {
      atomicAdd(out, contrib);               // out pre-zeroed by ph_zero_kernel
    }
  }
  // --- block 0 wave 0: gather all 24 contributions, write out ---
  if (use_ws && blk == 0 && wid == 0) {
    float v = 0.0f;
    if (lane < 24) {
      while (true) {
        unsigned long long r = atomicAdd(&ws64[lane], 0ull);  // device-coherent read
        if ((unsigned)r == FLAGMAGIC) { v = __uint_as_float((unsigned)(r >> 32)); break; }
      }
    }
    for (int off = 32; off > 0; off >>= 1) v += __shfl_xor(v, off);
    if (lane == 0) out[0] = v;
  }
}

extern "C" void kernel_launch(void* const* d_in, const int* in_sizes, int n_in,
                              void* d_out, int out_size, void* d_ws, size_t ws_size,
                              hipStream_t stream) {
  const float* x = (const float*)d_in[0];
  float* out = (float*)d_out;
  if (ws_size >= 24 * sizeof(unsigned long long)) {
    ph_pass_kernel<<<24, NT, 0, stream>>>(x, out, (unsigned long long*)d_ws, 1);
  } else {
    ph_zero_kernel<<<1, 1, 0, stream>>>(out);
    ph_pass_kernel<<<24, NT, 0, stream>>>(x, out, nullptr, 0);
  }
}